// Round 4
// baseline (553.405 us; speedup 1.0000x reference)
//
#include <hip/hip_runtime.h>
#include <stdint.h>

typedef __attribute__((ext_vector_type(8))) short bf16x8;   // 8 bf16 in 4 VGPRs
typedef __attribute__((ext_vector_type(4))) float f32x4;
typedef __attribute__((ext_vector_type(4))) unsigned short us4;
typedef unsigned short ushort;
typedef unsigned int uint;

#define MFMA16(a,b,c) __builtin_amdgcn_mfma_f32_16x16x32_bf16((a),(b),(c),0,0,0)

__device__ __forceinline__ ushort f2bf(float f){
  uint u = __builtin_bit_cast(uint, f);
  return (ushort)((u + 0x7fffu + ((u>>16)&1u)) >> 16);   // RTNE
}
__device__ __forceinline__ float bf2f(ushort h){
  return __builtin_bit_cast(float, ((uint)h)<<16);
}
__device__ __forceinline__ void gll16(const void* g, void* l){
  // async global->LDS, 16B per lane; LDS dest must be wave-uniform base (HW adds lane*16)
  __builtin_amdgcn_global_load_lds((const __attribute__((address_space(1))) void*)g,
                                   (__attribute__((address_space(3))) void*)l, 16, 0, 0);
}

// ---------------- generic 128x128 GEMM core (A row-major [.,K], B^T row-major [N,K], bf16) ---
// SPLIT: C = Ah*Bh + Ah*Bl + Al*Bh  (split-precision bf16 hi/lo)
template<bool SPLIT, int BK>
__device__ __forceinline__ void gemm_core(
    const char* __restrict__ Ah, const char* __restrict__ Al,
    const char* __restrict__ Bh, const char* __restrict__ Bl,
    int K, int lda, int ldb, int m0, int n0,
    f32x4 acc[4][4], char* sAh, char* sAl, char* sBh, char* sBl)
{
  constexpr int ROWB = BK*2;               // bytes per LDS row
  constexpr int CHUNKS = 128*ROWB/1024;    // 1KB wave-chunks per tile
  constexpr int XM = ((ROWB/16)-1) & 7;    // XOR-swizzle mask (16B granules per row)
  const int tid = threadIdx.x;
  const int wave = tid>>6, lane = tid&63;
  const int l15 = lane&15, l4 = lane>>4;
  const int wr = (wave>>1)*64, wc = (wave&1)*64;
  const int nsteps = K / BK;
  for (int kt = 0; kt < nsteps; ++kt) {
    const int kb0 = kt*ROWB;
    for (int c = wave; c < CHUNKS; c += 4) {
      const int p = (c<<10) + (lane<<4);
      const int row = p / ROWB;
      const int gk = (p % ROWB) ^ ((row & XM)<<4);   // pre-swizzled global source
      gll16(Ah + (size_t)(m0+row)*lda + kb0 + gk, sAh + (c<<10));
      gll16(Bh + (size_t)(n0+row)*ldb + kb0 + gk, sBh + (c<<10));
      if constexpr (SPLIT) {
        gll16(Al + (size_t)(m0+row)*lda + kb0 + gk, sAl + (c<<10));
        gll16(Bl + (size_t)(n0+row)*ldb + kb0 + gk, sBl + (c<<10));
      }
    }
    __syncthreads();
    #pragma unroll
    for (int ks = 0; ks < BK/32; ++ks) {
      bf16x8 ah[4], bh_[4], al[4], bl[4];
      #pragma unroll
      for (int i = 0; i < 4; ++i) {
        const int ar = wr + i*16 + l15;
        const int ao = ar*ROWB + ((ks*64 + l4*16) ^ ((ar & XM)<<4));
        ah[i] = *(const bf16x8*)(sAh + ao);
        const int br = wc + i*16 + l15;
        const int bo = br*ROWB + ((ks*64 + l4*16) ^ ((br & XM)<<4));
        bh_[i] = *(const bf16x8*)(sBh + bo);
        if constexpr (SPLIT) {
          al[i] = *(const bf16x8*)(sAl + ao);
          bl[i] = *(const bf16x8*)(sBl + bo);
        }
      }
      #pragma unroll
      for (int mi = 0; mi < 4; ++mi) {
        #pragma unroll
        for (int ni = 0; ni < 4; ++ni) {
          acc[mi][ni] = MFMA16(ah[mi], bh_[ni], acc[mi][ni]);
          if constexpr (SPLIT) {
            acc[mi][ni] = MFMA16(ah[mi], bl[ni], acc[mi][ni]);
            acc[mi][ni] = MFMA16(al[mi], bh_[ni], acc[mi][ni]);
          }
        }
      }
    }
    __syncthreads();
  }
}

// ---------------- weight prep: split WQ/WK into bf16 hi/lo, convert WV/W_O -------------------
__global__ __launch_bounds__(256) void k_prep(
    const float* __restrict__ wq, const float* __restrict__ wk,
    const float* __restrict__ wv, const float* __restrict__ wo,
    ushort* qh, ushort* ql_, ushort* kh, ushort* kl_, ushort* vb, ushort* ob)
{
  int i = blockIdx.x*256 + threadIdx.x;
  if (i >= 589824) return;
  float a = wq[i]; ushort h = f2bf(a); qh[i]=h; ql_[i]=f2bf(a - bf2f(h));
  float b = wk[i]; h = f2bf(b); kh[i]=h; kl_[i]=f2bf(b - bf2f(h));
  vb[i] = f2bf(wv[i]); ob[i] = f2bf(wo[i]);
}

// ---------------- fp32 [R][C] -> bf16 [C][R] transpose --------------------------------------
__global__ __launch_bounds__(256) void k_transpose(
    const float* __restrict__ in, ushort* __restrict__ out, int R, int C)
{
  __shared__ float t[32][33];
  const int bx = blockIdx.x*32, by = blockIdx.y*32;
  const int tx = threadIdx.x & 31, ty = threadIdx.x >> 5;
  #pragma unroll
  for (int i = 0; i < 4; ++i)
    t[ty + i*8][tx] = in[(size_t)(by + ty + i*8)*C + bx + tx];
  __syncthreads();
  #pragma unroll
  for (int i = 0; i < 4; ++i)
    out[(size_t)(bx + ty + i*8)*R + by + tx] = f2bf(t[tx][ty + i*8]);
}

// ---------------- layernorm over 768, fp32 in -> bf16 hi (+optional lo) ---------------------
// optional fused elementwise: oadd[row*768+idx] = in_row[idx] + badd[idx]  (out = z1 + b_down)
__global__ __launch_bounds__(256) void k_ln(
    const float* __restrict__ in, const float* __restrict__ g, const float* __restrict__ be,
    ushort* __restrict__ oh, ushort* __restrict__ ol,
    const float* __restrict__ badd, float* __restrict__ oadd)
{
  const int row = blockIdx.x, t = threadIdx.x;
  const float* r = in + (size_t)row*768;
  float v0 = r[t], v1 = r[t+256], v2 = r[t+512];
  float s = v0+v1+v2;
  float q = v0*v0 + v1*v1 + v2*v2;
  #pragma unroll
  for (int m = 32; m; m >>= 1) { s += __shfl_xor(s, m); q += __shfl_xor(q, m); }
  __shared__ float ss[4], sq[4];
  const int wave = t>>6, lane = t&63;
  if (!lane) { ss[wave] = s; sq[wave] = q; }
  __syncthreads();
  s = ss[0]+ss[1]+ss[2]+ss[3];
  q = sq[0]+sq[1]+sq[2]+sq[3];
  const float mu = s*(1.f/768.f);
  const float var = q*(1.f/768.f) - mu*mu;
  const float inv = rsqrtf(var + 1e-5f);
  const float vv[3] = {v0, v1, v2};
  #pragma unroll
  for (int i = 0; i < 3; ++i) {
    const int idx = t + i*256;
    const float u = (vv[i]-mu)*inv*g[idx] + be[idx];
    const ushort hi = f2bf(u);
    oh[(size_t)row*768 + idx] = hi;
    if (ol) ol[(size_t)row*768 + idx] = f2bf(u - bf2f(hi));
    if (oadd) oadd[(size_t)row*768 + idx] = vv[i] + badd[idx];
  }
}

// ---------------- QKV projection: z=0 Q(split), z=1 K(split), z=2 V(plain, writes V^T) ------
__global__ __launch_bounds__(256) void k_qkv(
    const ushort* __restrict__ uh, const ushort* __restrict__ ul,
    const ushort* __restrict__ wqh, const ushort* __restrict__ wql,
    const ushort* __restrict__ wkh, const ushort* __restrict__ wkl,
    const ushort* __restrict__ wvb,
    ushort* __restrict__ Qh, ushort* __restrict__ Ql,
    ushort* __restrict__ Kh, ushort* __restrict__ Kl,
    ushort* __restrict__ Vt)
{
  __shared__ char sA[8192], sA2[8192], sB[8192], sB2[8192];
  const int z = blockIdx.z;
  const int m0 = blockIdx.x*128, n0 = blockIdx.y*128;
  f32x4 acc[4][4] = {};
  if (z == 0)
    gemm_core<true,32>((const char*)uh, (const char*)ul, (const char*)wqh, (const char*)wql,
                       768, 1536, 1536, m0, n0, acc, sA, sA2, sB, sB2);
  else if (z == 1)
    gemm_core<true,32>((const char*)uh, (const char*)ul, (const char*)wkh, (const char*)wkl,
                       768, 1536, 1536, m0, n0, acc, sA, sA2, sB, sB2);
  else
    gemm_core<false,32>((const char*)uh, nullptr, (const char*)wvb, nullptr,
                        768, 1536, 1536, m0, n0, acc, sA, sA2, sB, sB2);

  const int tid = threadIdx.x, wave = tid>>6, lane = tid&63;
  const int l15 = lane&15, l4 = lane>>4;
  const int wr = (wave>>1)*64, wc = (wave&1)*64;
  if (z < 2) {
    ushort* __restrict__ Oh = z ? Kh : Qh;
    ushort* __restrict__ Ol = z ? Kl : Ql;
    #pragma unroll
    for (int mi = 0; mi < 4; ++mi) {
      #pragma unroll
      for (int ni = 0; ni < 4; ++ni) {
        const int he = n0 + wc + ni*16 + l15;
        const int h = he>>6, e = he&63;
        #pragma unroll
        for (int r = 0; r < 4; ++r) {
          const int n = m0 + wr + mi*16 + l4*4 + r;
          const int b = n>>11, l = n&2047;
          const size_t dst = ((size_t)((b*12+h)*2048 + l))*64 + e;
          const float c = acc[mi][ni][r];
          const ushort hi = f2bf(c);
          Oh[dst] = hi;
          Ol[dst] = f2bf(c - bf2f(hi));
        }
      }
    }
  } else {
    #pragma unroll
    for (int mi = 0; mi < 4; ++mi) {
      #pragma unroll
      for (int ni = 0; ni < 4; ++ni) {
        const int he = n0 + wc + ni*16 + l15;
        const int h = he>>6, e = he&63;
        const int n = m0 + wr + mi*16 + l4*4;
        const int b = n>>11, l = n&2047;
        us4 v;
        #pragma unroll
        for (int r = 0; r < 4; ++r) v[r] = f2bf(acc[mi][ni][r]);
        *(us4*)(Vt + ((size_t)((b*12+h)*64 + e))*2048 + l) = v;
      }
    }
  }
}

// ---------------- fused causal attention, split-KV, atomic fp32 partial accumulate ----------
// p = exp(30*tanh(S/8) - 30) is max-free -> partial (num, den) over disjoint KV ranges ADD.
// grid (80, 24): 80 = sum over qt of ceil((qt+1)/8) chunks; block 256 = 4 waves x 16 q rows.
__global__ __launch_bounds__(256) void k_attn(
    const ushort* __restrict__ Qh, const ushort* __restrict__ Ql,
    const ushort* __restrict__ Kh, const ushort* __restrict__ Kl,
    const ushort* __restrict__ Vt, const int* __restrict__ am,
    float* __restrict__ Onum, float* __restrict__ Oden)
{
  __shared__ char sKh[8192], sKl[8192], sV[8192];
  __shared__ char sP[4][2048];
  const int f = 79 - blockIdx.x;                // big chunks dispatch first
  int qt, c;
  if (f < 8)       { qt = f;               c = 0; }
  else if (f < 24) { int t = f-8;  qt = 8 +(t>>1); c = t&1; }
  else if (f < 48) { int t = f-24; qt = 16+ t/3;   c = t - (qt-16)*3; }
  else             { int t = f-48; qt = 24+(t>>2); c = t&3; }
  const int kt0 = c*8;
  const int kt1 = (kt0+8 < qt+1) ? kt0+8 : qt+1;

  const int bh = blockIdx.y;
  const int b = bh / 12;
  const int tid = threadIdx.x, wave = tid>>6, lane = tid&63;
  const int l15 = lane&15, l4 = lane>>4;

  const size_t qoff = ((size_t)bh*2048 + qt*64 + wave*16 + l15)*64 + l4*8;
  const bf16x8 q_h0 = *(const bf16x8*)(Qh + qoff);
  const bf16x8 q_h1 = *(const bf16x8*)(Qh + qoff + 32);
  const bf16x8 q_l0 = *(const bf16x8*)(Ql + qoff);
  const bf16x8 q_l1 = *(const bf16x8*)(Ql + qoff + 32);

  f32x4 oacc[4] = {};
  float dsum[4] = {0.f, 0.f, 0.f, 0.f};
  const char* Kh_t = (const char*)(Kh + (size_t)bh*2048*64);
  const char* Kl_t = (const char*)(Kl + (size_t)bh*2048*64);
  const char* Vt_b = (const char*)(Vt + (size_t)bh*64*2048);

  for (int kt = kt0; kt < kt1; ++kt) {
    // stage K_hi/K_lo [64 key][64 e] and V^T [64 e][64 key] tiles, XOR-swizzled via source
    for (int cc = wave; cc < 24; cc += 4) {
      const int p = ((cc&7)<<10) + (lane<<4);
      const int row = p >> 7;
      const int gkb = (p & 127) ^ ((row&7)<<4);
      const char* gsrc; char* lbase;
      if (cc < 8)       { gsrc = Kh_t + (size_t)(kt*64+row)*128 + gkb; lbase = sKh + ((cc&7)<<10); }
      else if (cc < 16) { gsrc = Kl_t + (size_t)(kt*64+row)*128 + gkb; lbase = sKl + ((cc&7)<<10); }
      else              { gsrc = Vt_b + (size_t)row*4096 + kt*128 + gkb; lbase = sV + ((cc&7)<<10); }
      gll16(gsrc, lbase);
    }
    __syncthreads();

    // S = Q K^T (3-term split product)
    f32x4 s[4] = {};
    #pragma unroll
    for (int ks = 0; ks < 2; ++ks) {
      bf16x8 kbh[4], kbl[4];
      #pragma unroll
      for (int nt = 0; nt < 4; ++nt) {
        const int key = nt*16 + l15;
        const int byte = key*128 + ((ks*64 + l4*16) ^ ((key&7)<<4));
        kbh[nt] = *(const bf16x8*)(sKh + byte);
        kbl[nt] = *(const bf16x8*)(sKl + byte);
      }
      const bf16x8 qh_ = ks ? q_h1 : q_h0;
      const bf16x8 ql_ = ks ? q_l1 : q_l0;
      #pragma unroll
      for (int nt = 0; nt < 4; ++nt) {
        s[nt] = MFMA16(qh_, kbh[nt], s[nt]);
        s[nt] = MFMA16(qh_, kbl[nt], s[nt]);
        s[nt] = MFMA16(ql_, kbh[nt], s[nt]);
      }
    }

    // p = exp(-60/(1+e^{2*S/8})); fast rcp is inf-safe: rcp(inf)=0 -> p=1 saturated
    const bool diag = (kt == qt);
    #pragma unroll
    for (int nt = 0; nt < 4; ++nt) {
      const int key_g = kt*64 + nt*16 + l15;
      const float mv = (float)am[b*2048 + key_g];
      #pragma unroll
      for (int r = 0; r < 4; ++r) {
        const float es = __expf(0.25f*s[nt][r]);           // e^{2s}, s = raw/8
        float p = __expf(-60.f*__builtin_amdgcn_rcpf(1.f + es)) * mv;
        if (diag && key_g > qt*64 + wave*16 + l4*4 + r) p = 0.f;
        dsum[r] += p;
        const int qi = l4*4 + r;
        const int byte = qi*128 + ((nt*32 + l15*2) ^ ((qi&7)<<4));
        *(ushort*)(sP[wave] + byte) = f2bf(p);
      }
    }

    // O += P V
    #pragma unroll
    for (int ks = 0; ks < 2; ++ks) {
      const int abyte = l15*128 + ((ks*64 + l4*16) ^ ((l15&7)<<4));
      const bf16x8 pa = *(const bf16x8*)(sP[wave] + abyte);
      #pragma unroll
      for (int et = 0; et < 4; ++et) {
        const int e_l = et*16 + l15;
        const int vbyte = e_l*128 + ((ks*64 + l4*16) ^ ((e_l&7)<<4));
        const bf16x8 vb = *(const bf16x8*)(sV + vbyte);
        oacc[et] = MFMA16(pa, vb, oacc[et]);
      }
    }
    __syncthreads();
  }

  // reduce row-denominators across the 16-lane l15 groups, then atomically combine partials
  #pragma unroll
  for (int r = 0; r < 4; ++r) {
    float d = dsum[r];
    d += __shfl_xor(d, 1); d += __shfl_xor(d, 2);
    d += __shfl_xor(d, 4); d += __shfl_xor(d, 8);
    dsum[r] = d;
  }
  const int qrow = qt*64 + wave*16 + l4*4;
  if (l15 == 0) {
    #pragma unroll
    for (int r = 0; r < 4; ++r)
      unsafeAtomicAdd(&Oden[bh*2048 + qrow + r], dsum[r]);
  }
  #pragma unroll
  for (int et = 0; et < 4; ++et) {
    #pragma unroll
    for (int r = 0; r < 4; ++r)
      unsafeAtomicAdd(&Onum[((size_t)bh*2048 + qrow + r)*64 + et*16 + l15], oacc[et][r]);
  }
}

// ---------------- normalize attention partials -> bf16 O_cat; also z1 = x (init for k_wo) ---
__global__ __launch_bounds__(256) void k_norm(
    const float* __restrict__ Onum, const float* __restrict__ Oden,
    const float* __restrict__ x, ushort* __restrict__ Oc, float* __restrict__ z1)
{
  const int i = blockIdx.x*256 + threadIdx.x;    // f32x4 units over [24][2048][64]
  const int row = i >> 4;                        // bh*2048 + l
  const int e0 = (i & 15)*4;
  const int bh = row >> 11, l = row & 2047;
  const int b = bh / 12, h = bh - b*12;
  const float inv = 1.f / Oden[row];
  const f32x4 v = *(const f32x4*)(Onum + (size_t)i*4);
  us4 o;
  #pragma unroll
  for (int j = 0; j < 4; ++j) o[j] = f2bf(v[j]*inv);
  const size_t dst = ((size_t)(b*2048 + l))*768 + h*64 + e0;
  *(us4*)(Oc + dst) = o;
  *(f32x4*)(z1 + dst) = *(const f32x4*)(x + dst);   // z1 init = x; k_wo accumulates attn
}

// ---------------- W_O GEMM, split-K=4, atomic accumulate into z1 (pre-init = x) -------------
__global__ __launch_bounds__(256) void k_wo(
    const ushort* __restrict__ oc, const ushort* __restrict__ wob,
    float* __restrict__ z1)
{
  __shared__ char sA[8192], sB[8192];
  const int m0 = blockIdx.x*128, n0 = blockIdx.y*128;
  const int kz = blockIdx.z;               // K chunk: 192 elements = 384 bytes
  f32x4 acc[4][4] = {};
  gemm_core<false,32>((const char*)oc + kz*384, nullptr, (const char*)wob + kz*384, nullptr,
                      192, 1536, 1536, m0, n0, acc, sA, nullptr, sB, nullptr);
  const int tid = threadIdx.x, wave = tid>>6, lane = tid&63;
  const int l15 = lane&15, l4 = lane>>4;
  const int wr = (wave>>1)*64, wc = (wave&1)*64;
  #pragma unroll
  for (int mi = 0; mi < 4; ++mi) {
    #pragma unroll
    for (int ni = 0; ni < 4; ++ni) {
      const int d = n0 + wc + ni*16 + l15;
      #pragma unroll
      for (int r = 0; r < 4; ++r) {
        const int n = m0 + wr + mi*16 + l4*4 + r;
        unsafeAtomicAdd(&z1[(size_t)n*768 + d], acc[mi][ni][r]);
      }
    }
  }
}

// ---------------- MLP up: v3 = gelu(v1 @ W_up + b_up) ---------------------------------------
__global__ __launch_bounds__(256) void k_up(
    const ushort* __restrict__ v1, const ushort* __restrict__ wupT,
    const float* __restrict__ bup, ushort* __restrict__ v3)
{
  __shared__ char sA[8192], sB[8192];
  const int m0 = blockIdx.x*128, n0 = blockIdx.y*128;
  f32x4 acc[4][4] = {};
  gemm_core<false,32>((const char*)v1, nullptr, (const char*)wupT, nullptr,
                      768, 1536, 1536, m0, n0, acc, sA, nullptr, sB, nullptr);
  const int tid = threadIdx.x, wave = tid>>6, lane = tid&63;
  const int l15 = lane&15, l4 = lane>>4;
  const int wr = (wave>>1)*64, wc = (wave&1)*64;
  #pragma unroll
  for (int mi = 0; mi < 4; ++mi) {
    #pragma unroll
    for (int ni = 0; ni < 4; ++ni) {
      const int j = n0 + wc + ni*16 + l15;
      const float bj = bup[j];
      #pragma unroll
      for (int r = 0; r < 4; ++r) {
        const int n = m0 + wr + mi*16 + l4*4 + r;
        const float c = acc[mi][ni][r] + bj;
        const float ge = 0.5f*c*(1.f + erff(c*0.70710678118654752f));
        v3[(size_t)n*9216 + j] = f2bf(ge);
      }
    }
  }
}

// ---------------- MLP down, split-K=8, atomic accumulate into out (pre-init z1+b) -----------
__global__ __launch_bounds__(256) void k_down(
    const ushort* __restrict__ v3, const ushort* __restrict__ wdnT,
    float* __restrict__ out)
{
  __shared__ char sA[8192], sB[8192];
  const int m0 = blockIdx.x*128, n0 = blockIdx.y*128;
  const int kz = blockIdx.z;               // K chunk: 1152 elements = 2304 bytes
  f32x4 acc[4][4] = {};
  gemm_core<false,32>((const char*)v3 + kz*2304, nullptr, (const char*)wdnT + kz*2304, nullptr,
                      1152, 18432, 18432, m0, n0, acc, sA, nullptr, sB, nullptr);
  const int tid = threadIdx.x, wave = tid>>6, lane = tid&63;
  const int l15 = lane&15, l4 = lane>>4;
  const int wr = (wave>>1)*64, wc = (wave&1)*64;
  #pragma unroll
  for (int mi = 0; mi < 4; ++mi) {
    #pragma unroll
    for (int ni = 0; ni < 4; ++ni) {
      const int d = n0 + wc + ni*16 + l15;
      #pragma unroll
      for (int r = 0; r < 4; ++r) {
        const int n = m0 + wr + mi*16 + l4*4 + r;
        unsafeAtomicAdd(&out[(size_t)n*768 + d], acc[mi][ni][r]);
      }
    }
  }
}

extern "C" void kernel_launch(void* const* d_in, const int* in_sizes, int n_in,
                              void* d_out, int out_size, void* d_ws, size_t ws_size,
                              hipStream_t stream) {
  const float* x   = (const float*)d_in[0];
  const int*   am  = (const int*)d_in[1];
  const float* WQ  = (const float*)d_in[2];
  const float* WK  = (const float*)d_in[3];
  const float* WV  = (const float*)d_in[4];
  const float* g1  = (const float*)d_in[5];
  const float* b1  = (const float*)d_in[6];
  const float* g2  = (const float*)d_in[7];
  const float* b2  = (const float*)d_in[8];
  const float* WO  = (const float*)d_in[9];
  const float* Wup = (const float*)d_in[10];
  const float* bup = (const float*)d_in[11];
  const float* Wdn = (const float*)d_in[12];
  const float* bdn = (const float*)d_in[13];
  float* out = (float*)d_out;

  char* w = (char*)d_ws;
  // weight conversions (persistent through their consumers)
  ushort* wqh  = (ushort*)(w + 0);
  ushort* wql  = (ushort*)(w + 1179648);
  ushort* wkh  = (ushort*)(w + 2359296);
  ushort* wkl  = (ushort*)(w + 3538944);
  ushort* wvb  = (ushort*)(w + 4718592);
  ushort* wob  = (ushort*)(w + 5898240);
  ushort* wupT = (ushort*)(w + 7077888);    // [9216][768] bf16
  ushort* wdnT = (ushort*)(w + 21233664);   // [768][9216] bf16
  float*  z1   = (float*) (w + 35389440);   // [4096][768] fp32
  ushort* v1h  = (ushort*)(w + 47972352);   // [4096][768] bf16
  char*  pool  = w + 54263808;              // 75.5MB pool (attn-phase bufs, then v3)
  ushort* uh   = (ushort*)(pool + 0);
  ushort* ul   = (ushort*)(pool + 6291456);
  ushort* Qh_  = (ushort*)(pool + 12582912);
  ushort* Ql_  = (ushort*)(pool + 18874368);
  ushort* Kh_  = (ushort*)(pool + 25165824);
  ushort* Kl_  = (ushort*)(pool + 31457280);
  ushort* Vt_  = (ushort*)(pool + 37748736);
  ushort* oc   = (ushort*)(pool + 44040192);
  float* Onum  = (float*)(pool + 0);        // overlays dead uh/ul during attn phase (12.58MB)
  float* Oden  = (float*)(pool + 50331648); // after oc (192KB)
  ushort* v3   = (ushort*)(pool + 0);       // overlays whole pool in MLP phase
  const size_t NEED = 54263808u + 75497472u;
  if (ws_size < NEED) return;               // fail cleanly rather than corrupt

  k_prep<<<2304, 256, 0, stream>>>(WQ, WK, WV, WO, wqh, wql, wkh, wkl, wvb, wob);
  k_transpose<<<dim3(288, 24), 256, 0, stream>>>(Wup, wupT, 768, 9216);
  k_transpose<<<dim3(24, 288), 256, 0, stream>>>(Wdn, wdnT, 9216, 768);
  k_ln<<<4096, 256, 0, stream>>>(x, g1, b1, uh, ul, nullptr, nullptr);
  k_qkv<<<dim3(32, 6, 3), 256, 0, stream>>>(uh, ul, wqh, wql, wkh, wkl, wvb,
                                            Qh_, Ql_, Kh_, Kl_, Vt_);
  // attn partials (zero-init after k_qkv has consumed uh/ul, which Onum overlays)
  hipMemsetAsync(Onum, 0, 12582912, stream);
  hipMemsetAsync(Oden, 0, 196608, stream);
  k_attn<<<dim3(80, 24), 256, 0, stream>>>(Qh_, Ql_, Kh_, Kl_, Vt_, am, Onum, Oden);
  // normalize attn + z1 = x (k_wo then accumulates attn@W_O^T into z1, split-K=4)
  k_norm<<<3072, 256, 0, stream>>>(Onum, Oden, x, oc, z1);
  k_wo<<<dim3(32, 6, 4), 256, 0, stream>>>(oc, wob, z1);
  // LN2 + fused out-init (out = z1 + b_down); k_down then accumulates (split-K=8)
  k_ln<<<4096, 256, 0, stream>>>(z1, g2, b2, v1h, nullptr, bdn, out);
  k_up<<<dim3(32, 72), 256, 0, stream>>>(v1h, wupT, bup, v3);
  k_down<<<dim3(32, 6, 8), 256, 0, stream>>>(v3, wdnT, out);
}

// Round 5
// 525.733 us; speedup vs baseline: 1.0526x; 1.0526x over previous
//
#include <hip/hip_runtime.h>
#include <stdint.h>

typedef __attribute__((ext_vector_type(8))) short bf16x8;   // 8 bf16 in 4 VGPRs
typedef __attribute__((ext_vector_type(4))) float f32x4;
typedef __attribute__((ext_vector_type(4))) unsigned short us4;
typedef unsigned short ushort;
typedef unsigned int uint;

#define MFMA16(a,b,c) __builtin_amdgcn_mfma_f32_16x16x32_bf16((a),(b),(c),0,0,0)

__device__ __forceinline__ ushort f2bf(float f){
  uint u = __builtin_bit_cast(uint, f);
  return (ushort)((u + 0x7fffu + ((u>>16)&1u)) >> 16);   // RTNE
}
__device__ __forceinline__ float bf2f(ushort h){
  return __builtin_bit_cast(float, ((uint)h)<<16);
}
__device__ __forceinline__ void gll16(const void* g, void* l){
  // async global->LDS, 16B per lane; LDS dest must be wave-uniform base (HW adds lane*16)
  __builtin_amdgcn_global_load_lds((const __attribute__((address_space(1))) void*)g,
                                   (__attribute__((address_space(3))) void*)l, 16, 0, 0);
}

// ---------------- generic 128x128 GEMM core (A row-major [.,K], B^T row-major [N,K], bf16) ---
// BK=64 ONLY: ROWB=128 -> XM=7 -> XOR swizzle spans all 32 banks (BK=32 gives 4-way
// conflicts, measured 7.08M SQ_LDS_BANK_CONFLICT in round 4 -- do not shrink BK).
// SPLIT: C = Ah*Bh + Ah*Bl + Al*Bh  (split-precision bf16 hi/lo)
template<bool SPLIT>
__device__ __forceinline__ void gemm_core(
    const char* __restrict__ Ah, const char* __restrict__ Al,
    const char* __restrict__ Bh, const char* __restrict__ Bl,
    int K, int lda, int ldb, int m0, int n0,
    f32x4 acc[4][4], char* sAh, char* sAl, char* sBh, char* sBl)
{
  constexpr int ROWB = 128;                // bytes per LDS row (BK=64)
  constexpr int CHUNKS = 16;               // 1KB wave-chunks per 16KB tile
  const int tid = threadIdx.x;
  const int wave = tid>>6, lane = tid&63;
  const int l15 = lane&15, l4 = lane>>4;
  const int wr = (wave>>1)*64, wc = (wave&1)*64;
  const int nsteps = K >> 6;
  for (int kt = 0; kt < nsteps; ++kt) {
    const int kb0 = kt*ROWB;
    for (int c = wave; c < CHUNKS; c += 4) {
      const int p = (c<<10) + (lane<<4);
      const int row = p >> 7;
      const int gk = (p & 127) ^ ((row & 7)<<4);     // pre-swizzled global source
      gll16(Ah + (size_t)(m0+row)*lda + kb0 + gk, sAh + (c<<10));
      gll16(Bh + (size_t)(n0+row)*ldb + kb0 + gk, sBh + (c<<10));
      if constexpr (SPLIT) {
        gll16(Al + (size_t)(m0+row)*lda + kb0 + gk, sAl + (c<<10));
        gll16(Bl + (size_t)(n0+row)*ldb + kb0 + gk, sBl + (c<<10));
      }
    }
    __syncthreads();
    #pragma unroll
    for (int ks = 0; ks < 2; ++ks) {
      bf16x8 ah[4], bh_[4], al[4], bl[4];
      #pragma unroll
      for (int i = 0; i < 4; ++i) {
        const int ar = wr + i*16 + l15;
        const int ao = ar*ROWB + ((ks*64 + l4*16) ^ ((ar & 7)<<4));
        ah[i] = *(const bf16x8*)(sAh + ao);
        const int br = wc + i*16 + l15;
        const int bo = br*ROWB + ((ks*64 + l4*16) ^ ((br & 7)<<4));
        bh_[i] = *(const bf16x8*)(sBh + bo);
        if constexpr (SPLIT) {
          al[i] = *(const bf16x8*)(sAl + ao);
          bl[i] = *(const bf16x8*)(sBl + bo);
        }
      }
      #pragma unroll
      for (int mi = 0; mi < 4; ++mi) {
        #pragma unroll
        for (int ni = 0; ni < 4; ++ni) {
          acc[mi][ni] = MFMA16(ah[mi], bh_[ni], acc[mi][ni]);
          if constexpr (SPLIT) {
            acc[mi][ni] = MFMA16(ah[mi], bl[ni], acc[mi][ni]);
            acc[mi][ni] = MFMA16(al[mi], bh_[ni], acc[mi][ni]);
          }
        }
      }
    }
    __syncthreads();
  }
}

// ---------------- weight prep: split WQ/WK into bf16 hi/lo, convert WV/W_O -------------------
__global__ __launch_bounds__(256) void k_prep(
    const float* __restrict__ wq, const float* __restrict__ wk,
    const float* __restrict__ wv, const float* __restrict__ wo,
    ushort* qh, ushort* ql_, ushort* kh, ushort* kl_, ushort* vb, ushort* ob)
{
  int i = blockIdx.x*256 + threadIdx.x;
  if (i >= 589824) return;
  float a = wq[i]; ushort h = f2bf(a); qh[i]=h; ql_[i]=f2bf(a - bf2f(h));
  float b = wk[i]; h = f2bf(b); kh[i]=h; kl_[i]=f2bf(b - bf2f(h));
  vb[i] = f2bf(wv[i]); ob[i] = f2bf(wo[i]);
}

// ---------------- fp32 [R][C] -> bf16 [C][R] transpose --------------------------------------
__global__ __launch_bounds__(256) void k_transpose(
    const float* __restrict__ in, ushort* __restrict__ out, int R, int C)
{
  __shared__ float t[32][33];
  const int bx = blockIdx.x*32, by = blockIdx.y*32;
  const int tx = threadIdx.x & 31, ty = threadIdx.x >> 5;
  #pragma unroll
  for (int i = 0; i < 4; ++i)
    t[ty + i*8][tx] = in[(size_t)(by + ty + i*8)*C + bx + tx];
  __syncthreads();
  #pragma unroll
  for (int i = 0; i < 4; ++i)
    out[(size_t)(bx + ty + i*8)*R + by + tx] = f2bf(t[tx][ty + i*8]);
}

// ---------------- layernorm over 768, fp32 in -> bf16 hi (+optional lo) ---------------------
// optional fused elementwise: oadd[row*768+idx] = in_row[idx] + badd[idx]  (out = z1 + b_down)
__global__ __launch_bounds__(256) void k_ln(
    const float* __restrict__ in, const float* __restrict__ g, const float* __restrict__ be,
    ushort* __restrict__ oh, ushort* __restrict__ ol,
    const float* __restrict__ badd, float* __restrict__ oadd)
{
  const int row = blockIdx.x, t = threadIdx.x;
  const float* r = in + (size_t)row*768;
  float v0 = r[t], v1 = r[t+256], v2 = r[t+512];
  float s = v0+v1+v2;
  float q = v0*v0 + v1*v1 + v2*v2;
  #pragma unroll
  for (int m = 32; m; m >>= 1) { s += __shfl_xor(s, m); q += __shfl_xor(q, m); }
  __shared__ float ss[4], sq[4];
  const int wave = t>>6, lane = t&63;
  if (!lane) { ss[wave] = s; sq[wave] = q; }
  __syncthreads();
  s = ss[0]+ss[1]+ss[2]+ss[3];
  q = sq[0]+sq[1]+sq[2]+sq[3];
  const float mu = s*(1.f/768.f);
  const float var = q*(1.f/768.f) - mu*mu;
  const float inv = rsqrtf(var + 1e-5f);
  const float vv[3] = {v0, v1, v2};
  #pragma unroll
  for (int i = 0; i < 3; ++i) {
    const int idx = t + i*256;
    const float u = (vv[i]-mu)*inv*g[idx] + be[idx];
    const ushort hi = f2bf(u);
    oh[(size_t)row*768 + idx] = hi;
    if (ol) ol[(size_t)row*768 + idx] = f2bf(u - bf2f(hi));
    if (oadd) oadd[(size_t)row*768 + idx] = vv[i] + badd[idx];
  }
}

// ---------------- QKV projection: z=0 Q(split), z=1 K(split), z=2 V(plain, writes V^T) ------
__global__ __launch_bounds__(256) void k_qkv(
    const ushort* __restrict__ uh, const ushort* __restrict__ ul,
    const ushort* __restrict__ wqh, const ushort* __restrict__ wql,
    const ushort* __restrict__ wkh, const ushort* __restrict__ wkl,
    const ushort* __restrict__ wvb,
    ushort* __restrict__ Qh, ushort* __restrict__ Ql,
    ushort* __restrict__ Kh, ushort* __restrict__ Kl,
    ushort* __restrict__ Vt)
{
  __shared__ char sA[16384], sA2[16384], sB[16384], sB2[16384];  // 64KB; grid is 2.25 blk/CU anyway
  const int z = blockIdx.z;
  const int m0 = blockIdx.x*128, n0 = blockIdx.y*128;
  f32x4 acc[4][4] = {};
  if (z == 0)
    gemm_core<true>((const char*)uh, (const char*)ul, (const char*)wqh, (const char*)wql,
                    768, 1536, 1536, m0, n0, acc, sA, sA2, sB, sB2);
  else if (z == 1)
    gemm_core<true>((const char*)uh, (const char*)ul, (const char*)wkh, (const char*)wkl,
                    768, 1536, 1536, m0, n0, acc, sA, sA2, sB, sB2);
  else
    gemm_core<false>((const char*)uh, nullptr, (const char*)wvb, nullptr,
                     768, 1536, 1536, m0, n0, acc, sA, sA2, sB, sB2);

  const int tid = threadIdx.x, wave = tid>>6, lane = tid&63;
  const int l15 = lane&15, l4 = lane>>4;
  const int wr = (wave>>1)*64, wc = (wave&1)*64;
  if (z < 2) {
    ushort* __restrict__ Oh = z ? Kh : Qh;
    ushort* __restrict__ Ol = z ? Kl : Ql;
    #pragma unroll
    for (int mi = 0; mi < 4; ++mi) {
      #pragma unroll
      for (int ni = 0; ni < 4; ++ni) {
        const int he = n0 + wc + ni*16 + l15;
        const int h = he>>6, e = he&63;
        #pragma unroll
        for (int r = 0; r < 4; ++r) {
          const int n = m0 + wr + mi*16 + l4*4 + r;
          const int b = n>>11, l = n&2047;
          const size_t dst = ((size_t)((b*12+h)*2048 + l))*64 + e;
          const float c = acc[mi][ni][r];
          const ushort hi = f2bf(c);
          Oh[dst] = hi;
          Ol[dst] = f2bf(c - bf2f(hi));
        }
      }
    }
  } else {
    #pragma unroll
    for (int mi = 0; mi < 4; ++mi) {
      #pragma unroll
      for (int ni = 0; ni < 4; ++ni) {
        const int he = n0 + wc + ni*16 + l15;
        const int h = he>>6, e = he&63;
        const int n = m0 + wr + mi*16 + l4*4;
        const int b = n>>11, l = n&2047;
        us4 v;
        #pragma unroll
        for (int r = 0; r < 4; ++r) v[r] = f2bf(acc[mi][ni][r]);
        *(us4*)(Vt + ((size_t)((b*12+h)*64 + e))*2048 + l) = v;
      }
    }
  }
}

// ---------------- fused causal attention, split-KV, atomic fp32 partial accumulate ----------
// p = exp(30*tanh(S/8) - 30) is max-free -> partial (num, den) over disjoint KV ranges ADD.
// grid (80, 24): 80 = sum over qt of ceil((qt+1)/8) chunks; block 256 = 4 waves x 16 q rows.
__global__ __launch_bounds__(256) void k_attn(
    const ushort* __restrict__ Qh, const ushort* __restrict__ Ql,
    const ushort* __restrict__ Kh, const ushort* __restrict__ Kl,
    const ushort* __restrict__ Vt, const int* __restrict__ am,
    float* __restrict__ Onum, float* __restrict__ Oden)
{
  __shared__ char sKh[8192], sKl[8192], sV[8192];
  __shared__ char sP[4][2048];
  const int f = 79 - blockIdx.x;                // big chunks dispatch first
  int qt, c;
  if (f < 8)       { qt = f;               c = 0; }
  else if (f < 24) { int t = f-8;  qt = 8 +(t>>1); c = t&1; }
  else if (f < 48) { int t = f-24; qt = 16+ t/3;   c = t - (qt-16)*3; }
  else             { int t = f-48; qt = 24+(t>>2); c = t&3; }
  const int kt0 = c*8;
  const int kt1 = (kt0+8 < qt+1) ? kt0+8 : qt+1;

  const int bh = blockIdx.y;
  const int b = bh / 12;
  const int tid = threadIdx.x, wave = tid>>6, lane = tid&63;
  const int l15 = lane&15, l4 = lane>>4;

  const size_t qoff = ((size_t)bh*2048 + qt*64 + wave*16 + l15)*64 + l4*8;
  const bf16x8 q_h0 = *(const bf16x8*)(Qh + qoff);
  const bf16x8 q_h1 = *(const bf16x8*)(Qh + qoff + 32);
  const bf16x8 q_l0 = *(const bf16x8*)(Ql + qoff);
  const bf16x8 q_l1 = *(const bf16x8*)(Ql + qoff + 32);

  f32x4 oacc[4] = {};
  float dsum[4] = {0.f, 0.f, 0.f, 0.f};
  const char* Kh_t = (const char*)(Kh + (size_t)bh*2048*64);
  const char* Kl_t = (const char*)(Kl + (size_t)bh*2048*64);
  const char* Vt_b = (const char*)(Vt + (size_t)bh*64*2048);

  for (int kt = kt0; kt < kt1; ++kt) {
    // stage K_hi/K_lo [64 key][64 e] and V^T [64 e][64 key] tiles, XOR-swizzled via source
    for (int cc = wave; cc < 24; cc += 4) {
      const int p = ((cc&7)<<10) + (lane<<4);
      const int row = p >> 7;
      const int gkb = (p & 127) ^ ((row&7)<<4);
      const char* gsrc; char* lbase;
      if (cc < 8)       { gsrc = Kh_t + (size_t)(kt*64+row)*128 + gkb; lbase = sKh + ((cc&7)<<10); }
      else if (cc < 16) { gsrc = Kl_t + (size_t)(kt*64+row)*128 + gkb; lbase = sKl + ((cc&7)<<10); }
      else              { gsrc = Vt_b + (size_t)row*4096 + kt*128 + gkb; lbase = sV + ((cc&7)<<10); }
      gll16(gsrc, lbase);
    }
    __syncthreads();

    // S = Q K^T (3-term split product)
    f32x4 s[4] = {};
    #pragma unroll
    for (int ks = 0; ks < 2; ++ks) {
      bf16x8 kbh[4], kbl[4];
      #pragma unroll
      for (int nt = 0; nt < 4; ++nt) {
        const int key = nt*16 + l15;
        const int byte = key*128 + ((ks*64 + l4*16) ^ ((key&7)<<4));
        kbh[nt] = *(const bf16x8*)(sKh + byte);
        kbl[nt] = *(const bf16x8*)(sKl + byte);
      }
      const bf16x8 qh_ = ks ? q_h1 : q_h0;
      const bf16x8 ql_ = ks ? q_l1 : q_l0;
      #pragma unroll
      for (int nt = 0; nt < 4; ++nt) {
        s[nt] = MFMA16(qh_, kbh[nt], s[nt]);
        s[nt] = MFMA16(qh_, kbl[nt], s[nt]);
        s[nt] = MFMA16(ql_, kbh[nt], s[nt]);
      }
    }

    // p = exp(-60/(1+e^{2*S/8})); fast rcp is inf-safe: rcp(inf)=0 -> p=1 saturated
    const bool diag = (kt == qt);
    #pragma unroll
    for (int nt = 0; nt < 4; ++nt) {
      const int key_g = kt*64 + nt*16 + l15;
      const float mv = (float)am[b*2048 + key_g];
      #pragma unroll
      for (int r = 0; r < 4; ++r) {
        const float es = __expf(0.25f*s[nt][r]);           // e^{2s}, s = raw/8
        float p = __expf(-60.f*__builtin_amdgcn_rcpf(1.f + es)) * mv;
        if (diag && key_g > qt*64 + wave*16 + l4*4 + r) p = 0.f;
        dsum[r] += p;
        const int qi = l4*4 + r;
        const int byte = qi*128 + ((nt*32 + l15*2) ^ ((qi&7)<<4));
        *(ushort*)(sP[wave] + byte) = f2bf(p);
      }
    }

    // O += P V
    #pragma unroll
    for (int ks = 0; ks < 2; ++ks) {
      const int abyte = l15*128 + ((ks*64 + l4*16) ^ ((l15&7)<<4));
      const bf16x8 pa = *(const bf16x8*)(sP[wave] + abyte);
      #pragma unroll
      for (int et = 0; et < 4; ++et) {
        const int e_l = et*16 + l15;
        const int vbyte = e_l*128 + ((ks*64 + l4*16) ^ ((e_l&7)<<4));
        const bf16x8 vb = *(const bf16x8*)(sV + vbyte);
        oacc[et] = MFMA16(pa, vb, oacc[et]);
      }
    }
    __syncthreads();
  }

  // reduce row-denominators across the 16-lane l15 groups, then atomically combine partials
  #pragma unroll
  for (int r = 0; r < 4; ++r) {
    float d = dsum[r];
    d += __shfl_xor(d, 1); d += __shfl_xor(d, 2);
    d += __shfl_xor(d, 4); d += __shfl_xor(d, 8);
    dsum[r] = d;
  }
  const int qrow = qt*64 + wave*16 + l4*4;
  if (l15 == 0) {
    #pragma unroll
    for (int r = 0; r < 4; ++r)
      unsafeAtomicAdd(&Oden[bh*2048 + qrow + r], dsum[r]);
  }
  #pragma unroll
  for (int et = 0; et < 4; ++et) {
    #pragma unroll
    for (int r = 0; r < 4; ++r)
      unsafeAtomicAdd(&Onum[((size_t)bh*2048 + qrow + r)*64 + et*16 + l15], oacc[et][r]);
  }
}

// ---------------- normalize attention partials -> bf16 O_cat; also z1 = x (init for k_wo) ---
__global__ __launch_bounds__(256) void k_norm(
    const float* __restrict__ Onum, const float* __restrict__ Oden,
    const float* __restrict__ x, ushort* __restrict__ Oc, float* __restrict__ z1)
{
  const int i = blockIdx.x*256 + threadIdx.x;    // f32x4 units over [24][2048][64]
  const int row = i >> 4;                        // bh*2048 + l
  const int e0 = (i & 15)*4;
  const int bh = row >> 11, l = row & 2047;
  const int b = bh / 12, h = bh - b*12;
  const float inv = 1.f / Oden[row];
  const f32x4 v = *(const f32x4*)(Onum + (size_t)i*4);
  us4 o;
  #pragma unroll
  for (int j = 0; j < 4; ++j) o[j] = f2bf(v[j]*inv);
  const size_t dst = ((size_t)(b*2048 + l))*768 + h*64 + e0;
  *(us4*)(Oc + dst) = o;
  *(f32x4*)(z1 + dst) = *(const f32x4*)(x + dst);   // z1 init = x; k_wo accumulates attn
}

// ---------------- W_O GEMM, split-K=4, atomic accumulate into z1 (pre-init = x) -------------
__global__ __launch_bounds__(256) void k_wo(
    const ushort* __restrict__ oc, const ushort* __restrict__ wob,
    float* __restrict__ z1)
{
  __shared__ char sA[16384], sB[16384];
  const int m0 = blockIdx.x*128, n0 = blockIdx.y*128;
  const int kz = blockIdx.z;               // K chunk: 192 elements = 384 bytes, 3 K-steps
  f32x4 acc[4][4] = {};
  gemm_core<false>((const char*)oc + kz*384, nullptr, (const char*)wob + kz*384, nullptr,
                   192, 1536, 1536, m0, n0, acc, sA, nullptr, sB, nullptr);
  const int tid = threadIdx.x, wave = tid>>6, lane = tid&63;
  const int l15 = lane&15, l4 = lane>>4;
  const int wr = (wave>>1)*64, wc = (wave&1)*64;
  #pragma unroll
  for (int mi = 0; mi < 4; ++mi) {
    #pragma unroll
    for (int ni = 0; ni < 4; ++ni) {
      const int d = n0 + wc + ni*16 + l15;
      #pragma unroll
      for (int r = 0; r < 4; ++r) {
        const int n = m0 + wr + mi*16 + l4*4 + r;
        unsafeAtomicAdd(&z1[(size_t)n*768 + d], acc[mi][ni][r]);
      }
    }
  }
}

// ---------------- MLP up: v3 = gelu(v1 @ W_up + b_up) ---------------------------------------
__global__ __launch_bounds__(256) void k_up(
    const ushort* __restrict__ v1, const ushort* __restrict__ wupT,
    const float* __restrict__ bup, ushort* __restrict__ v3)
{
  __shared__ char sA[16384], sB[16384];
  const int m0 = blockIdx.x*128, n0 = blockIdx.y*128;
  f32x4 acc[4][4] = {};
  gemm_core<false>((const char*)v1, nullptr, (const char*)wupT, nullptr,
                   768, 1536, 1536, m0, n0, acc, sA, nullptr, sB, nullptr);
  const int tid = threadIdx.x, wave = tid>>6, lane = tid&63;
  const int l15 = lane&15, l4 = lane>>4;
  const int wr = (wave>>1)*64, wc = (wave&1)*64;
  #pragma unroll
  for (int mi = 0; mi < 4; ++mi) {
    #pragma unroll
    for (int ni = 0; ni < 4; ++ni) {
      const int j = n0 + wc + ni*16 + l15;
      const float bj = bup[j];
      #pragma unroll
      for (int r = 0; r < 4; ++r) {
        const int n = m0 + wr + mi*16 + l4*4 + r;
        const float c = acc[mi][ni][r] + bj;
        const float ge = 0.5f*c*(1.f + erff(c*0.70710678118654752f));
        v3[(size_t)n*9216 + j] = f2bf(ge);
      }
    }
  }
}

// ---------------- MLP down, split-K=8, atomic accumulate into out (pre-init z1+b) -----------
__global__ __launch_bounds__(256) void k_down(
    const ushort* __restrict__ v3, const ushort* __restrict__ wdnT,
    float* __restrict__ out)
{
  __shared__ char sA[16384], sB[16384];
  const int m0 = blockIdx.x*128, n0 = blockIdx.y*128;
  const int kz = blockIdx.z;               // K chunk: 1152 elements = 2304 bytes, 18 K-steps
  f32x4 acc[4][4] = {};
  gemm_core<false>((const char*)v3 + kz*2304, nullptr, (const char*)wdnT + kz*2304, nullptr,
                   1152, 18432, 18432, m0, n0, acc, sA, nullptr, sB, nullptr);
  const int tid = threadIdx.x, wave = tid>>6, lane = tid&63;
  const int l15 = lane&15, l4 = lane>>4;
  const int wr = (wave>>1)*64, wc = (wave&1)*64;
  #pragma unroll
  for (int mi = 0; mi < 4; ++mi) {
    #pragma unroll
    for (int ni = 0; ni < 4; ++ni) {
      const int d = n0 + wc + ni*16 + l15;
      #pragma unroll
      for (int r = 0; r < 4; ++r) {
        const int n = m0 + wr + mi*16 + l4*4 + r;
        unsafeAtomicAdd(&out[(size_t)n*768 + d], acc[mi][ni][r]);
      }
    }
  }
}

extern "C" void kernel_launch(void* const* d_in, const int* in_sizes, int n_in,
                              void* d_out, int out_size, void* d_ws, size_t ws_size,
                              hipStream_t stream) {
  const float* x   = (const float*)d_in[0];
  const int*   am  = (const int*)d_in[1];
  const float* WQ  = (const float*)d_in[2];
  const float* WK  = (const float*)d_in[3];
  const float* WV  = (const float*)d_in[4];
  const float* g1  = (const float*)d_in[5];
  const float* b1  = (const float*)d_in[6];
  const float* g2  = (const float*)d_in[7];
  const float* b2  = (const float*)d_in[8];
  const float* WO  = (const float*)d_in[9];
  const float* Wup = (const float*)d_in[10];
  const float* bup = (const float*)d_in[11];
  const float* Wdn = (const float*)d_in[12];
  const float* bdn = (const float*)d_in[13];
  float* out = (float*)d_out;

  char* w = (char*)d_ws;
  // weight conversions (persistent through their consumers)
  ushort* wqh  = (ushort*)(w + 0);
  ushort* wql  = (ushort*)(w + 1179648);
  ushort* wkh  = (ushort*)(w + 2359296);
  ushort* wkl  = (ushort*)(w + 3538944);
  ushort* wvb  = (ushort*)(w + 4718592);
  ushort* wob  = (ushort*)(w + 5898240);
  ushort* wupT = (ushort*)(w + 7077888);    // [9216][768] bf16
  ushort* wdnT = (ushort*)(w + 21233664);   // [768][9216] bf16
  float*  z1   = (float*) (w + 35389440);   // [4096][768] fp32
  ushort* v1h  = (ushort*)(w + 47972352);   // [4096][768] bf16
  char*  pool  = w + 54263808;              // 75.5MB pool (attn-phase bufs, then v3)
  ushort* uh   = (ushort*)(pool + 0);
  ushort* ul   = (ushort*)(pool + 6291456);
  ushort* Qh_  = (ushort*)(pool + 12582912);
  ushort* Ql_  = (ushort*)(pool + 18874368);
  ushort* Kh_  = (ushort*)(pool + 25165824);
  ushort* Kl_  = (ushort*)(pool + 31457280);
  ushort* Vt_  = (ushort*)(pool + 37748736);
  ushort* oc   = (ushort*)(pool + 44040192);
  float* Onum  = (float*)(pool + 0);        // overlays dead uh/ul during attn phase (12.58MB)
  float* Oden  = (float*)(pool + 50331648); // after oc (192KB)
  ushort* v3   = (ushort*)(pool + 0);       // overlays whole pool in MLP phase
  const size_t NEED = 54263808u + 75497472u;
  if (ws_size < NEED) return;               // fail cleanly rather than corrupt

  k_prep<<<2304, 256, 0, stream>>>(WQ, WK, WV, WO, wqh, wql, wkh, wkl, wvb, wob);
  k_transpose<<<dim3(288, 24), 256, 0, stream>>>(Wup, wupT, 768, 9216);
  k_transpose<<<dim3(24, 288), 256, 0, stream>>>(Wdn, wdnT, 9216, 768);
  k_ln<<<4096, 256, 0, stream>>>(x, g1, b1, uh, ul, nullptr, nullptr);
  k_qkv<<<dim3(32, 6, 3), 256, 0, stream>>>(uh, ul, wqh, wql, wkh, wkl, wvb,
                                            Qh_, Ql_, Kh_, Kl_, Vt_);
  // attn partials (zero-init after k_qkv has consumed uh/ul, which Onum overlays)
  hipMemsetAsync(Onum, 0, 12582912, stream);
  hipMemsetAsync(Oden, 0, 196608, stream);
  k_attn<<<dim3(80, 24), 256, 0, stream>>>(Qh_, Ql_, Kh_, Kl_, Vt_, am, Onum, Oden);
  // normalize attn + z1 = x (k_wo then accumulates attn@W_O^T into z1, split-K=4)
  k_norm<<<3072, 256, 0, stream>>>(Onum, Oden, x, oc, z1);
  k_wo<<<dim3(32, 6, 4), 256, 0, stream>>>(oc, wob, z1);
  // LN2 + fused out-init (out = z1 + b_down); k_down then accumulates (split-K=8)
  k_ln<<<4096, 256, 0, stream>>>(z1, g2, b2, v1h, nullptr, bdn, out);
  k_up<<<dim3(32, 72), 256, 0, stream>>>(v1h, wupT, bup, v3);
  k_down<<<dim3(32, 6, 8), 256, 0, stream>>>(v3, wdnT, out);
}

// Round 6
// 482.086 us; speedup vs baseline: 1.1479x; 1.0905x over previous
//
#include <hip/hip_runtime.h>
#include <stdint.h>

typedef __attribute__((ext_vector_type(8))) short bf16x8;   // 8 bf16 in 4 VGPRs
typedef __attribute__((ext_vector_type(4))) float f32x4;
typedef __attribute__((ext_vector_type(4))) unsigned short us4;
typedef unsigned short ushort;
typedef unsigned int uint;

#define MFMA16(a,b,c) __builtin_amdgcn_mfma_f32_16x16x32_bf16((a),(b),(c),0,0,0)

__device__ __forceinline__ ushort f2bf(float f){
  uint u = __builtin_bit_cast(uint, f);
  return (ushort)((u + 0x7fffu + ((u>>16)&1u)) >> 16);   // RTNE
}
__device__ __forceinline__ float bf2f(ushort h){
  return __builtin_bit_cast(float, ((uint)h)<<16);
}
__device__ __forceinline__ void gll16(const void* g, void* l){
  // async global->LDS, 16B per lane; LDS dest is wave-uniform base (HW adds lane*16)
  __builtin_amdgcn_global_load_lds((const __attribute__((address_space(1))) void*)g,
                                   (__attribute__((address_space(3))) void*)l, 16, 0, 0);
}

// ================= 128x128 GEMM core (m97-style, BK=64 only: swizzle needs 128B rows) =======
template<bool SPLIT>
__device__ __forceinline__ void gemm_core(
    const char* __restrict__ Ah, const char* __restrict__ Al,
    const char* __restrict__ Bh, const char* __restrict__ Bl,
    int K, int lda, int ldb, int m0, int n0,
    f32x4 acc[4][4], char* sAh, char* sAl, char* sBh, char* sBl)
{
  const int tid = threadIdx.x;
  const int wave = tid>>6, lane = tid&63;
  const int l15 = lane&15, l4 = lane>>4;
  const int wr = (wave>>1)*64, wc = (wave&1)*64;
  const int nsteps = K >> 6;
  for (int kt = 0; kt < nsteps; ++kt) {
    const int kb0 = kt*128;
    for (int c = wave; c < 16; c += 4) {
      const int p = (c<<10) + (lane<<4);
      const int row = p >> 7;
      const int gk = (p & 127) ^ ((row & 7)<<4);     // pre-swizzled global source
      gll16(Ah + (size_t)(m0+row)*lda + kb0 + gk, sAh + (c<<10));
      gll16(Bh + (size_t)(n0+row)*ldb + kb0 + gk, sBh + (c<<10));
      if constexpr (SPLIT) {
        gll16(Al + (size_t)(m0+row)*lda + kb0 + gk, sAl + (c<<10));
        gll16(Bl + (size_t)(n0+row)*ldb + kb0 + gk, sBl + (c<<10));
      }
    }
    __syncthreads();
    #pragma unroll
    for (int ks = 0; ks < 2; ++ks) {
      bf16x8 ah[4], bh_[4], al[4], bl[4];
      #pragma unroll
      for (int i = 0; i < 4; ++i) {
        const int ar = wr + i*16 + l15;
        const int ao = ar*128 + ((ks*64 + l4*16) ^ ((ar & 7)<<4));
        ah[i] = *(const bf16x8*)(sAh + ao);
        const int br = wc + i*16 + l15;
        const int bo = br*128 + ((ks*64 + l4*16) ^ ((br & 7)<<4));
        bh_[i] = *(const bf16x8*)(sBh + bo);
        if constexpr (SPLIT) {
          al[i] = *(const bf16x8*)(sAl + ao);
          bl[i] = *(const bf16x8*)(sBl + bo);
        }
      }
      #pragma unroll
      for (int mi = 0; mi < 4; ++mi) {
        #pragma unroll
        for (int ni = 0; ni < 4; ++ni) {
          acc[mi][ni] = MFMA16(ah[mi], bh_[ni], acc[mi][ni]);
          if constexpr (SPLIT) {
            acc[mi][ni] = MFMA16(ah[mi], bl[ni], acc[mi][ni]);
            acc[mi][ni] = MFMA16(al[mi], bh_[ni], acc[mi][ni]);
          }
        }
      }
    }
    __syncthreads();
  }
}

// ================= 256x192 counted-vmcnt pipelined GEMM (8 waves, dbuf 112KB LDS) ===========
// Units/K-tile: B0,B1,B2 (192x64 = 24KB), A0..A3 (256x64 = 32KB); issue order
// B0,B1,B2,A0,A2,A1,A3 (A0/A2 feed quadrants 0-1, A1/A3 feed 2-3).  Per K-tile:
// half1: vmcnt(2) barrier; read B+q0; issue u0,u1; mfma; read q1; issue u2,u3; mfma
// half2: vmcnt(4) barrier; read q2; issue u4,u5; mfma; read q3; issue u6; mfma
// Loads stay in flight across barriers (T4); never drained to 0 except final tile.
__device__ __forceinline__ void gemm8(
    const char* __restrict__ A, const char* __restrict__ B, int lda, int ldb,
    int m0, int n0, int nt, f32x4 acc[8][3], char* lds)
{
  const int tid = threadIdx.x;
  const int wave = tid>>6, lane = tid&63;
  const int l15 = lane&15, l4 = lane>>4;
  const int wm = wave>>2, wn = wave&3;
  const int urow = wave*8 + (lane>>3);     // row within 64-row unit (wave covers 8 rows)
  const int ucol = (lane&7)<<4;            // byte within 128B row

  auto ISSUE = [&](int t, int u, int buf){
    const int kb0 = t<<7;
    char* lb = lds + buf*57344;
    if (u < 3) {                                        // B unit
      const int lr = u*64 + urow;
      gll16(B + (size_t)(n0+lr)*ldb + kb0 + (ucol ^ ((lr&7)<<4)),
            lb + 32768 + u*8192 + wave*1024);
    } else {                                            // A unit, order A0,A2,A1,A3
      const int au = (u==3) ? 0 : (u==4) ? 2 : (u==5) ? 1 : 3;
      const int lr = au*64 + urow;
      gll16(A + (size_t)(m0+lr)*lda + kb0 + (ucol ^ ((lr&7)<<4)),
            lb + au*8192 + wave*1024);
    }
  };

  #pragma unroll
  for (int u = 0; u < 7; ++u) ISSUE(0, u, 0);

  int cur = 0;
  for (int t = 0; t < nt; ++t) {
    const int nxt = cur^1;
    const char* L = lds + cur*57344;
    // ---------------- half 1 ----------------
    asm volatile("s_waitcnt vmcnt(2)" ::: "memory");
    __builtin_amdgcn_s_barrier();
    __builtin_amdgcn_sched_barrier(0);
    bf16x8 bf_[3][2], af[2][2];
    #pragma unroll
    for (int j = 0; j < 3; ++j) {
      const int br = wn*48 + j*16 + l15;
      bf_[j][0] = *(const bf16x8*)(L + 32768 + br*128 + ((l4*16)      ^ ((br&7)<<4)));
      bf_[j][1] = *(const bf16x8*)(L + 32768 + br*128 + ((64 + l4*16) ^ ((br&7)<<4)));
    }
    #pragma unroll
    for (int i = 0; i < 2; ++i) {
      const int ar = wm*128 + i*16 + l15;
      af[i][0] = *(const bf16x8*)(L + ar*128 + ((l4*16)      ^ ((ar&7)<<4)));
      af[i][1] = *(const bf16x8*)(L + ar*128 + ((64 + l4*16) ^ ((ar&7)<<4)));
    }
    if (t+1 < nt) { ISSUE(t+1, 0, nxt); ISSUE(t+1, 1, nxt); }
    __builtin_amdgcn_s_setprio(1);
    #pragma unroll
    for (int i = 0; i < 2; ++i)
      #pragma unroll
      for (int j = 0; j < 3; ++j) {
        acc[i][j] = MFMA16(af[i][0], bf_[j][0], acc[i][j]);
        acc[i][j] = MFMA16(af[i][1], bf_[j][1], acc[i][j]);
      }
    __builtin_amdgcn_s_setprio(0);
    #pragma unroll
    for (int i = 0; i < 2; ++i) {
      const int ar = wm*128 + (2+i)*16 + l15;
      af[i][0] = *(const bf16x8*)(L + ar*128 + ((l4*16)      ^ ((ar&7)<<4)));
      af[i][1] = *(const bf16x8*)(L + ar*128 + ((64 + l4*16) ^ ((ar&7)<<4)));
    }
    if (t+1 < nt) { ISSUE(t+1, 2, nxt); ISSUE(t+1, 3, nxt); }
    __builtin_amdgcn_s_setprio(1);
    #pragma unroll
    for (int i = 0; i < 2; ++i)
      #pragma unroll
      for (int j = 0; j < 3; ++j) {
        acc[2+i][j] = MFMA16(af[i][0], bf_[j][0], acc[2+i][j]);
        acc[2+i][j] = MFMA16(af[i][1], bf_[j][1], acc[2+i][j]);
      }
    __builtin_amdgcn_s_setprio(0);
    // ---------------- half 2 ----------------
    if (t+1 < nt) asm volatile("s_waitcnt vmcnt(4)" ::: "memory");
    else          asm volatile("s_waitcnt vmcnt(0)" ::: "memory");
    __builtin_amdgcn_s_barrier();
    __builtin_amdgcn_sched_barrier(0);
    #pragma unroll
    for (int i = 0; i < 2; ++i) {
      const int ar = wm*128 + (4+i)*16 + l15;
      af[i][0] = *(const bf16x8*)(L + ar*128 + ((l4*16)      ^ ((ar&7)<<4)));
      af[i][1] = *(const bf16x8*)(L + ar*128 + ((64 + l4*16) ^ ((ar&7)<<4)));
    }
    if (t+1 < nt) { ISSUE(t+1, 4, nxt); ISSUE(t+1, 5, nxt); }
    __builtin_amdgcn_s_setprio(1);
    #pragma unroll
    for (int i = 0; i < 2; ++i)
      #pragma unroll
      for (int j = 0; j < 3; ++j) {
        acc[4+i][j] = MFMA16(af[i][0], bf_[j][0], acc[4+i][j]);
        acc[4+i][j] = MFMA16(af[i][1], bf_[j][1], acc[4+i][j]);
      }
    __builtin_amdgcn_s_setprio(0);
    #pragma unroll
    for (int i = 0; i < 2; ++i) {
      const int ar = wm*128 + (6+i)*16 + l15;
      af[i][0] = *(const bf16x8*)(L + ar*128 + ((l4*16)      ^ ((ar&7)<<4)));
      af[i][1] = *(const bf16x8*)(L + ar*128 + ((64 + l4*16) ^ ((ar&7)<<4)));
    }
    if (t+1 < nt) { ISSUE(t+1, 6, nxt); }
    __builtin_amdgcn_s_setprio(1);
    #pragma unroll
    for (int i = 0; i < 2; ++i)
      #pragma unroll
      for (int j = 0; j < 3; ++j) {
        acc[6+i][j] = MFMA16(af[i][0], bf_[j][0], acc[6+i][j]);
        acc[6+i][j] = MFMA16(af[i][1], bf_[j][1], acc[6+i][j]);
      }
    __builtin_amdgcn_s_setprio(0);
    cur = nxt;
  }
}

// ================= shared device helpers =====================================================
__device__ __forceinline__ void ln_row(
    const float* __restrict__ in, const float* __restrict__ g, const float* __restrict__ be,
    ushort* __restrict__ oh, ushort* __restrict__ ol,
    const float* __restrict__ badd, float* __restrict__ oadd, int row)
{
  const int t = threadIdx.x;
  const float* r = in + (size_t)row*768;
  float v0 = r[t], v1 = r[t+256], v2 = r[t+512];
  float s = v0+v1+v2;
  float q = v0*v0 + v1*v1 + v2*v2;
  #pragma unroll
  for (int m = 32; m; m >>= 1) { s += __shfl_xor(s, m); q += __shfl_xor(q, m); }
  __shared__ float ss[4], sq[4];
  const int wave = t>>6, lane = t&63;
  if (!lane) { ss[wave] = s; sq[wave] = q; }
  __syncthreads();
  s = ss[0]+ss[1]+ss[2]+ss[3];
  q = sq[0]+sq[1]+sq[2]+sq[3];
  const float mu = s*(1.f/768.f);
  const float var = q*(1.f/768.f) - mu*mu;
  const float inv = rsqrtf(var + 1e-5f);
  const float vv[3] = {v0, v1, v2};
  #pragma unroll
  for (int i = 0; i < 3; ++i) {
    const int idx = t + i*256;
    const float u = (vv[i]-mu)*inv*g[idx] + be[idx];
    const ushort hi = f2bf(u);
    oh[(size_t)row*768 + idx] = hi;
    if (ol) ol[(size_t)row*768 + idx] = f2bf(u - bf2f(hi));
    if (oadd) oadd[(size_t)row*768 + idx] = vv[i] + badd[idx];
  }
}

__device__ __forceinline__ void transpose_tile(
    const float* __restrict__ in, ushort* __restrict__ out, int R, int C, int bx, int by)
{
  __shared__ float tt[32][33];
  const int tx = threadIdx.x & 31, ty = threadIdx.x >> 5;
  #pragma unroll
  for (int i = 0; i < 4; ++i)
    tt[ty + i*8][tx] = in[(size_t)(by + ty + i*8)*C + bx + tx];
  __syncthreads();
  #pragma unroll
  for (int i = 0; i < 4; ++i)
    out[(size_t)(bx + ty + i*8)*R + by + tx] = f2bf(tt[tx][ty + i*8]);
}

// ================= merged pre-pass: transposes + weight prep + LN1 (independent work) =======
__global__ __launch_bounds__(256) void k_pre(
    const float* __restrict__ Wup, ushort* __restrict__ wupT,
    const float* __restrict__ Wdn, ushort* __restrict__ wdnT,
    const float* __restrict__ wq, const float* __restrict__ wk,
    const float* __restrict__ wv, const float* __restrict__ wo,
    ushort* qh, ushort* ql_, ushort* kh, ushort* kl_, ushort* vb, ushort* ob,
    const float* __restrict__ x, const float* __restrict__ g1, const float* __restrict__ b1,
    ushort* __restrict__ uh, ushort* __restrict__ ul)
{
  const int bid = blockIdx.x;
  if (bid < 6912) {
    transpose_tile(Wup, wupT, 768, 9216, (bid%288)*32, (bid/288)*32);
  } else if (bid < 13824) {
    const int c = bid - 6912;
    transpose_tile(Wdn, wdnT, 9216, 768, (c%24)*32, (c/24)*32);
  } else if (bid < 16128) {
    const int i = (bid - 13824)*256 + threadIdx.x;   // 2304*256 = 589824 exact
    float a = wq[i]; ushort h = f2bf(a); qh[i]=h; ql_[i]=f2bf(a - bf2f(h));
    float b = wk[i]; h = f2bf(b); kh[i]=h; kl_[i]=f2bf(b - bf2f(h));
    vb[i] = f2bf(wv[i]); ob[i] = f2bf(wo[i]);
  } else {
    ln_row(x, g1, b1, uh, ul, nullptr, nullptr, bid - 16128);
  }
}

// ---------------- layernorm kernel (LN2 + fused out-init) -----------------------------------
__global__ __launch_bounds__(256) void k_ln(
    const float* __restrict__ in, const float* __restrict__ g, const float* __restrict__ be,
    ushort* __restrict__ oh, ushort* __restrict__ ol,
    const float* __restrict__ badd, float* __restrict__ oadd)
{
  ln_row(in, g, be, oh, ol, badd, oadd, blockIdx.x);
}

// ---------------- QKV projection: z=0 Q(split), z=1 K(split), z=2 V(plain, writes V^T) ------
__global__ __launch_bounds__(256) void k_qkv(
    const ushort* __restrict__ uh, const ushort* __restrict__ ul,
    const ushort* __restrict__ wqh, const ushort* __restrict__ wql,
    const ushort* __restrict__ wkh, const ushort* __restrict__ wkl,
    const ushort* __restrict__ wvb,
    ushort* __restrict__ Qh, ushort* __restrict__ Ql,
    ushort* __restrict__ Kh, ushort* __restrict__ Kl,
    ushort* __restrict__ Vt)
{
  __shared__ char sA[16384], sA2[16384], sB[16384], sB2[16384];
  const int z = blockIdx.z;
  const int m0 = blockIdx.x*128, n0 = blockIdx.y*128;
  f32x4 acc[4][4] = {};
  if (z == 0)
    gemm_core<true>((const char*)uh, (const char*)ul, (const char*)wqh, (const char*)wql,
                    768, 1536, 1536, m0, n0, acc, sA, sA2, sB, sB2);
  else if (z == 1)
    gemm_core<true>((const char*)uh, (const char*)ul, (const char*)wkh, (const char*)wkl,
                    768, 1536, 1536, m0, n0, acc, sA, sA2, sB, sB2);
  else
    gemm_core<false>((const char*)uh, nullptr, (const char*)wvb, nullptr,
                     768, 1536, 1536, m0, n0, acc, sA, sA2, sB, sB2);

  const int tid = threadIdx.x, wave = tid>>6, lane = tid&63;
  const int l15 = lane&15, l4 = lane>>4;
  const int wr = (wave>>1)*64, wc = (wave&1)*64;
  if (z < 2) {
    ushort* __restrict__ Oh = z ? Kh : Qh;
    ushort* __restrict__ Ol = z ? Kl : Ql;
    #pragma unroll
    for (int mi = 0; mi < 4; ++mi) {
      #pragma unroll
      for (int ni = 0; ni < 4; ++ni) {
        const int he = n0 + wc + ni*16 + l15;
        const int h = he>>6, e = he&63;
        #pragma unroll
        for (int r = 0; r < 4; ++r) {
          const int n = m0 + wr + mi*16 + l4*4 + r;
          const int b = n>>11, l = n&2047;
          const size_t dst = ((size_t)((b*12+h)*2048 + l))*64 + e;
          const float c = acc[mi][ni][r];
          const ushort hi = f2bf(c);
          Oh[dst] = hi;
          Ol[dst] = f2bf(c - bf2f(hi));
        }
      }
    }
  } else {
    #pragma unroll
    for (int mi = 0; mi < 4; ++mi) {
      #pragma unroll
      for (int ni = 0; ni < 4; ++ni) {
        const int he = n0 + wc + ni*16 + l15;
        const int h = he>>6, e = he&63;
        const int n = m0 + wr + mi*16 + l4*4;
        const int b = n>>11, l = n&2047;
        us4 v;
        #pragma unroll
        for (int r = 0; r < 4; ++r) v[r] = f2bf(acc[mi][ni][r]);
        *(us4*)(Vt + ((size_t)((b*12+h)*64 + e))*2048 + l) = v;
      }
    }
  }
}

// ---------------- fused causal attention, split-KV, atomic fp32 partial accumulate ----------
__global__ __launch_bounds__(256) void k_attn(
    const ushort* __restrict__ Qh, const ushort* __restrict__ Ql,
    const ushort* __restrict__ Kh, const ushort* __restrict__ Kl,
    const ushort* __restrict__ Vt, const int* __restrict__ am,
    float* __restrict__ Onum, float* __restrict__ Oden)
{
  __shared__ char sKh[8192], sKl[8192], sV[8192];
  __shared__ char sP[4][2048];
  const int f = 79 - blockIdx.x;                // big chunks dispatch first
  int qt, c;
  if (f < 8)       { qt = f;               c = 0; }
  else if (f < 24) { int t = f-8;  qt = 8 +(t>>1); c = t&1; }
  else if (f < 48) { int t = f-24; qt = 16+ t/3;   c = t - (qt-16)*3; }
  else             { int t = f-48; qt = 24+(t>>2); c = t&3; }
  const int kt0 = c*8;
  const int kt1 = (kt0+8 < qt+1) ? kt0+8 : qt+1;

  const int bh = blockIdx.y;
  const int b = bh / 12;
  const int tid = threadIdx.x, wave = tid>>6, lane = tid&63;
  const int l15 = lane&15, l4 = lane>>4;

  const size_t qoff = ((size_t)bh*2048 + qt*64 + wave*16 + l15)*64 + l4*8;
  const bf16x8 q_h0 = *(const bf16x8*)(Qh + qoff);
  const bf16x8 q_h1 = *(const bf16x8*)(Qh + qoff + 32);
  const bf16x8 q_l0 = *(const bf16x8*)(Ql + qoff);
  const bf16x8 q_l1 = *(const bf16x8*)(Ql + qoff + 32);

  f32x4 oacc[4] = {};
  float dsum[4] = {0.f, 0.f, 0.f, 0.f};
  const char* Kh_t = (const char*)(Kh + (size_t)bh*2048*64);
  const char* Kl_t = (const char*)(Kl + (size_t)bh*2048*64);
  const char* Vt_b = (const char*)(Vt + (size_t)bh*64*2048);

  for (int kt = kt0; kt < kt1; ++kt) {
    for (int cc = wave; cc < 24; cc += 4) {
      const int p = ((cc&7)<<10) + (lane<<4);
      const int row = p >> 7;
      const int gkb = (p & 127) ^ ((row&7)<<4);
      const char* gsrc; char* lbase;
      if (cc < 8)       { gsrc = Kh_t + (size_t)(kt*64+row)*128 + gkb; lbase = sKh + ((cc&7)<<10); }
      else if (cc < 16) { gsrc = Kl_t + (size_t)(kt*64+row)*128 + gkb; lbase = sKl + ((cc&7)<<10); }
      else              { gsrc = Vt_b + (size_t)row*4096 + kt*128 + gkb; lbase = sV + ((cc&7)<<10); }
      gll16(gsrc, lbase);
    }
    __syncthreads();

    f32x4 s[4] = {};
    #pragma unroll
    for (int ks = 0; ks < 2; ++ks) {
      bf16x8 kbh[4], kbl[4];
      #pragma unroll
      for (int nt = 0; nt < 4; ++nt) {
        const int key = nt*16 + l15;
        const int byte = key*128 + ((ks*64 + l4*16) ^ ((key&7)<<4));
        kbh[nt] = *(const bf16x8*)(sKh + byte);
        kbl[nt] = *(const bf16x8*)(sKl + byte);
      }
      const bf16x8 qh_ = ks ? q_h1 : q_h0;
      const bf16x8 ql_ = ks ? q_l1 : q_l0;
      #pragma unroll
      for (int nt = 0; nt < 4; ++nt) {
        s[nt] = MFMA16(qh_, kbh[nt], s[nt]);
        s[nt] = MFMA16(qh_, kbl[nt], s[nt]);
        s[nt] = MFMA16(ql_, kbh[nt], s[nt]);
      }
    }

    const bool diag = (kt == qt);
    #pragma unroll
    for (int nt = 0; nt < 4; ++nt) {
      const int key_g = kt*64 + nt*16 + l15;
      const float mv = (float)am[b*2048 + key_g];
      #pragma unroll
      for (int r = 0; r < 4; ++r) {
        const float es = __expf(0.25f*s[nt][r]);           // e^{2s}, s = raw/8
        float p = __expf(-60.f*__builtin_amdgcn_rcpf(1.f + es)) * mv;
        if (diag && key_g > qt*64 + wave*16 + l4*4 + r) p = 0.f;
        dsum[r] += p;
        const int qi = l4*4 + r;
        const int byte = qi*128 + ((nt*32 + l15*2) ^ ((qi&7)<<4));
        *(ushort*)(sP[wave] + byte) = f2bf(p);
      }
    }

    #pragma unroll
    for (int ks = 0; ks < 2; ++ks) {
      const int abyte = l15*128 + ((ks*64 + l4*16) ^ ((l15&7)<<4));
      const bf16x8 pa = *(const bf16x8*)(sP[wave] + abyte);
      #pragma unroll
      for (int et = 0; et < 4; ++et) {
        const int e_l = et*16 + l15;
        const int vbyte = e_l*128 + ((ks*64 + l4*16) ^ ((e_l&7)<<4));
        const bf16x8 vb = *(const bf16x8*)(sV + vbyte);
        oacc[et] = MFMA16(pa, vb, oacc[et]);
      }
    }
    __syncthreads();
  }

  #pragma unroll
  for (int r = 0; r < 4; ++r) {
    float d = dsum[r];
    d += __shfl_xor(d, 1); d += __shfl_xor(d, 2);
    d += __shfl_xor(d, 4); d += __shfl_xor(d, 8);
    dsum[r] = d;
  }
  const int qrow = qt*64 + wave*16 + l4*4;
  if (l15 == 0) {
    #pragma unroll
    for (int r = 0; r < 4; ++r)
      unsafeAtomicAdd(&Oden[bh*2048 + qrow + r], dsum[r]);
  }
  #pragma unroll
  for (int et = 0; et < 4; ++et) {
    #pragma unroll
    for (int r = 0; r < 4; ++r)
      unsafeAtomicAdd(&Onum[((size_t)bh*2048 + qrow + r)*64 + et*16 + l15], oacc[et][r]);
  }
}

// ---------------- normalize attention partials -> bf16 O_cat; also z1 = x (init for k_wo) ---
__global__ __launch_bounds__(256) void k_norm(
    const float* __restrict__ Onum, const float* __restrict__ Oden,
    const float* __restrict__ x, ushort* __restrict__ Oc, float* __restrict__ z1)
{
  const int i = blockIdx.x*256 + threadIdx.x;    // f32x4 units over [24][2048][64]
  const int row = i >> 4;                        // bh*2048 + l
  const int e0 = (i & 15)*4;
  const int bh = row >> 11, l = row & 2047;
  const int b = bh / 12, h = bh - b*12;
  const float inv = 1.f / Oden[row];
  const f32x4 v = *(const f32x4*)(Onum + (size_t)i*4);
  us4 o;
  #pragma unroll
  for (int j = 0; j < 4; ++j) o[j] = f2bf(v[j]*inv);
  const size_t dst = ((size_t)(b*2048 + l))*768 + h*64 + e0;
  *(us4*)(Oc + dst) = o;
  *(f32x4*)(z1 + dst) = *(const f32x4*)(x + dst);
}

// ---------------- W_O GEMM, split-K=4, atomic accumulate into z1 (pre-init = x) -------------
__global__ __launch_bounds__(256) void k_wo(
    const ushort* __restrict__ oc, const ushort* __restrict__ wob,
    float* __restrict__ z1)
{
  __shared__ char sA[16384], sB[16384];
  const int m0 = blockIdx.x*128, n0 = blockIdx.y*128;
  const int kz = blockIdx.z;               // K chunk: 192 elements = 384 bytes, 3 K-steps
  f32x4 acc[4][4] = {};
  gemm_core<false>((const char*)oc + kz*384, nullptr, (const char*)wob + kz*384, nullptr,
                   192, 1536, 1536, m0, n0, acc, sA, nullptr, sB, nullptr);
  const int tid = threadIdx.x, wave = tid>>6, lane = tid&63;
  const int l15 = lane&15, l4 = lane>>4;
  const int wr = (wave>>1)*64, wc = (wave&1)*64;
  #pragma unroll
  for (int mi = 0; mi < 4; ++mi) {
    #pragma unroll
    for (int ni = 0; ni < 4; ++ni) {
      const int d = n0 + wc + ni*16 + l15;
      #pragma unroll
      for (int r = 0; r < 4; ++r) {
        const int n = m0 + wr + mi*16 + l4*4 + r;
        unsafeAtomicAdd(&z1[(size_t)n*768 + d], acc[mi][ni][r]);
      }
    }
  }
}

// ---------------- MLP up (pipelined 256x192): v3 = gelu(v1 @ W_up + b_up) -------------------
__global__ __launch_bounds__(512, 2) void k_up8(
    const ushort* __restrict__ v1, const ushort* __restrict__ wupT,
    const float* __restrict__ bup, ushort* __restrict__ v3)
{
  __shared__ char lds[114688];
  const int m0 = blockIdx.x*256, n0 = blockIdx.y*192;
  f32x4 acc[8][3] = {};
  gemm8((const char*)v1, (const char*)wupT, 1536, 1536, m0, n0, 12, acc, lds);
  const int tid = threadIdx.x, wave = tid>>6, lane = tid&63;
  const int l15 = lane&15, l4 = lane>>4;
  const int wm = wave>>2, wn = wave&3;
  #pragma unroll
  for (int ni = 0; ni < 3; ++ni) {
    const int j = n0 + wn*48 + ni*16 + l15;
    const float bj = bup[j];
    #pragma unroll
    for (int mi = 0; mi < 8; ++mi) {
      #pragma unroll
      for (int r = 0; r < 4; ++r) {
        const int n = m0 + wm*128 + mi*16 + l4*4 + r;
        const float c = acc[mi][ni][r] + bj;
        v3[(size_t)n*9216 + j] = f2bf(0.5f*c*(1.f + erff(c*0.70710678118654752f)));
      }
    }
  }
}

// ---------------- MLP down (pipelined 256x192), split-K=4, atomics into out -----------------
__global__ __launch_bounds__(512, 2) void k_down8(
    const ushort* __restrict__ v3, const ushort* __restrict__ wdnT,
    float* __restrict__ out)
{
  __shared__ char lds[114688];
  const int m0 = blockIdx.x*256, n0 = blockIdx.y*192;
  const int kz = blockIdx.z;               // K chunk: 2304 elements = 4608 bytes, 18 K-tiles
  f32x4 acc[8][3] = {};
  gemm8((const char*)v3 + kz*4608, (const char*)wdnT + kz*4608, 18432, 18432,
        m0, n0, 18, acc, lds);
  const int tid = threadIdx.x, wave = tid>>6, lane = tid&63;
  const int l15 = lane&15, l4 = lane>>4;
  const int wm = wave>>2, wn = wave&3;
  #pragma unroll
  for (int ni = 0; ni < 3; ++ni) {
    const int d = n0 + wn*48 + ni*16 + l15;
    #pragma unroll
    for (int mi = 0; mi < 8; ++mi) {
      #pragma unroll
      for (int r = 0; r < 4; ++r) {
        const int n = m0 + wm*128 + mi*16 + l4*4 + r;
        unsafeAtomicAdd(&out[(size_t)n*768 + d], acc[mi][ni][r]);
      }
    }
  }
}

extern "C" void kernel_launch(void* const* d_in, const int* in_sizes, int n_in,
                              void* d_out, int out_size, void* d_ws, size_t ws_size,
                              hipStream_t stream) {
  const float* x   = (const float*)d_in[0];
  const int*   am  = (const int*)d_in[1];
  const float* WQ  = (const float*)d_in[2];
  const float* WK  = (const float*)d_in[3];
  const float* WV  = (const float*)d_in[4];
  const float* g1  = (const float*)d_in[5];
  const float* b1  = (const float*)d_in[6];
  const float* g2  = (const float*)d_in[7];
  const float* b2  = (const float*)d_in[8];
  const float* WO  = (const float*)d_in[9];
  const float* Wup = (const float*)d_in[10];
  const float* bup = (const float*)d_in[11];
  const float* Wdn = (const float*)d_in[12];
  const float* bdn = (const float*)d_in[13];
  float* out = (float*)d_out;

  char* w = (char*)d_ws;
  ushort* wqh  = (ushort*)(w + 0);
  ushort* wql  = (ushort*)(w + 1179648);
  ushort* wkh  = (ushort*)(w + 2359296);
  ushort* wkl  = (ushort*)(w + 3538944);
  ushort* wvb  = (ushort*)(w + 4718592);
  ushort* wob  = (ushort*)(w + 5898240);
  ushort* wupT = (ushort*)(w + 7077888);    // [9216][768] bf16
  ushort* wdnT = (ushort*)(w + 21233664);   // [768][9216] bf16
  float*  z1   = (float*) (w + 35389440);   // [4096][768] fp32
  ushort* v1h  = (ushort*)(w + 47972352);   // [4096][768] bf16
  char*  pool  = w + 54263808;              // 75.5MB pool (attn-phase bufs, then v3)
  ushort* uh   = (ushort*)(pool + 0);
  ushort* ul   = (ushort*)(pool + 6291456);
  ushort* Qh_  = (ushort*)(pool + 12582912);
  ushort* Ql_  = (ushort*)(pool + 18874368);
  ushort* Kh_  = (ushort*)(pool + 25165824);
  ushort* Kl_  = (ushort*)(pool + 31457280);
  ushort* Vt_  = (ushort*)(pool + 37748736);
  ushort* oc   = (ushort*)(pool + 44040192);
  float* Onum  = (float*)(pool + 0);        // overlays dead uh/ul during attn phase
  float* Oden  = (float*)(pool + 50331648);
  ushort* v3   = (ushort*)(pool + 0);       // overlays whole pool in MLP phase
  const size_t NEED = 54263808u + 75497472u;
  if (ws_size < NEED) return;

  // merged pre-pass: W_up^T, W_dn^T, WQ/WK hi-lo split, WV/WO cast, LN1
  k_pre<<<20224, 256, 0, stream>>>(Wup, wupT, Wdn, wdnT, WQ, WK, WV, WO,
                                   wqh, wql, wkh, wkl, wvb, wob, x, g1, b1, uh, ul);
  k_qkv<<<dim3(32, 6, 3), 256, 0, stream>>>(uh, ul, wqh, wql, wkh, wkl, wvb,
                                            Qh_, Ql_, Kh_, Kl_, Vt_);
  hipMemsetAsync(Onum, 0, 12582912, stream);
  hipMemsetAsync(Oden, 0, 196608, stream);
  k_attn<<<dim3(80, 24), 256, 0, stream>>>(Qh_, Ql_, Kh_, Kl_, Vt_, am, Onum, Oden);
  k_norm<<<3072, 256, 0, stream>>>(Onum, Oden, x, oc, z1);
  k_wo<<<dim3(32, 6, 4), 256, 0, stream>>>(oc, wob, z1);
  k_ln<<<4096, 256, 0, stream>>>(z1, g2, b2, v1h, nullptr, bdn, out);
  k_up8<<<dim3(16, 48), 512, 0, stream>>>(v1h, wupT, bup, v3);
  k_down8<<<dim3(16, 4, 4), 512, 0, stream>>>(v3, wdnT, out);
}